// Round 6
// baseline (608.093 us; speedup 1.0000x reference)
//
#include <hip/hip_runtime.h>
#include <math.h>

// Problem constants (from setup_inputs): B,V,C,D,H,W = 2,5,32,48,128,160
constexpr int B_ = 2;
constexpr int V_ = 5;
constexpr int C_ = 32;
constexpr int D_ = 48;
constexpr int H_ = 128;
constexpr int W_ = 160;
constexpr int HW_ = H_ * W_;               // 20480
constexpr int NVOX = B_ * D_ * HW_;        // 1,966,080
constexpr int PLANE = D_ * HW_;            // 983,040 (per-batch voxels)

typedef short short8 __attribute__((ext_vector_type(8)));
typedef float floatx4 __attribute__((ext_vector_type(4)));

// ---------------- small matrix helpers (device) ----------------

__device__ inline void combine4(const float* pm, float out[4][4]) {
    const float* E = pm;
    const float* K = pm + 16;
    for (int i = 0; i < 3; ++i)
        for (int j = 0; j < 4; ++j) {
            float a = 0.f;
            for (int k = 0; k < 3; ++k) a += K[i * 4 + k] * E[k * 4 + j];
            out[i][j] = a;
        }
    for (int j = 0; j < 4; ++j) out[3][j] = E[12 + j];
}

__device__ inline void invert4(const float A[4][4], float inv[4][4]) {
    float M[4][8];
    for (int i = 0; i < 4; ++i)
        for (int j = 0; j < 4; ++j) {
            M[i][j] = A[i][j];
            M[i][4 + j] = (i == j) ? 1.f : 0.f;
        }
    for (int col = 0; col < 4; ++col) {
        int piv = col;
        float best = fabsf(M[col][col]);
        for (int r = col + 1; r < 4; ++r) {
            float v = fabsf(M[r][col]);
            if (v > best) { best = v; piv = r; }
        }
        if (piv != col)
            for (int j = 0; j < 8; ++j) { float t = M[col][j]; M[col][j] = M[piv][j]; M[piv][j] = t; }
        float ip = 1.f / M[col][col];
        for (int j = 0; j < 8; ++j) M[col][j] *= ip;
        for (int r = 0; r < 4; ++r) {
            if (r == col) continue;
            float f = M[r][col];
            for (int j = 0; j < 8; ++j) M[r][j] -= f * M[col][j];
        }
    }
    for (int i = 0; i < 4; ++i)
        for (int j = 0; j < 4; ++j) inv[i][j] = M[i][4 + j];
}

__device__ inline unsigned bf_rne(float f) {
    unsigned u = __float_as_uint(f);
    return (u + 0x7FFFu + ((u >> 16) & 1u)) >> 16;   // RNE (values are finite)
}

__device__ inline void unpack8(uint4 u, float f[8]) {
    f[0] = __uint_as_float(u.x << 16);
    f[1] = __uint_as_float(u.x & 0xffff0000u);
    f[2] = __uint_as_float(u.y << 16);
    f[3] = __uint_as_float(u.y & 0xffff0000u);
    f[4] = __uint_as_float(u.z << 16);
    f[5] = __uint_as_float(u.z & 0xffff0000u);
    f[6] = __uint_as_float(u.w << 16);
    f[7] = __uint_as_float(u.w & 0xffff0000u);
}

// setup: (a) per b,v: P = src_proj @ inv(ref_proj) -> rt[12 floats]
//        (b) prepack conv weights as bf16 MFMA A-fragments:
//            A[m=tap=lane&15 (+16i)][k=ch=(lane>>4)*8+j], taps>=27 zero-padded
__global__ void setup_kernel(const float* __restrict__ proj, const float* __restrict__ wreg,
                             float* __restrict__ rt, unsigned* __restrict__ wtb) {
    int t = threadIdx.x;
    if (t < B_) {
        int b = t;
        float ref[4][4], inv[4][4];
        combine4(proj + (size_t)((b * V_ + 0) * 2) * 16, ref);
        invert4(ref, inv);
        for (int v = 1; v < V_; ++v) {
            float src[4][4];
            combine4(proj + (size_t)((b * V_ + v) * 2) * 16, src);
            float P[3][4];
            for (int i = 0; i < 3; ++i)
                for (int j = 0; j < 4; ++j) {
                    float a = 0.f;
                    for (int k = 0; k < 4; ++k) a += src[i][k] * inv[k][j];
                    P[i][j] = a;
                }
            float* o = rt + (size_t)(b * (V_ - 1) + (v - 1)) * 12;
            o[0] = P[0][0]; o[1] = P[0][1]; o[2] = P[0][2];
            o[3] = P[1][0]; o[4] = P[1][1]; o[5] = P[1][2];
            o[6] = P[2][0]; o[7] = P[2][1]; o[8] = P[2][2];
            o[9] = P[0][3]; o[10] = P[1][3]; o[11] = P[2][3];
        }
    }
    if (t < 128) {
        int i = t >> 6;          // which mfma (taps 0-15 / 16-31)
        int lane = t & 63;
        int q = lane >> 4;
        int l = lane & 15;
        int tap = i * 16 + l;
        unsigned u[4];
#pragma unroll
        for (int jj = 0; jj < 4; ++jj) {
            int ch0 = q * 8 + 2 * jj;
            float v0 = (tap < 27) ? wreg[ch0 * 27 + tap] : 0.f;
            float v1 = (tap < 27) ? wreg[(ch0 + 1) * 27 + tap] : 0.f;
            u[jj] = bf_rne(v0) | (bf_rne(v1) << 16);
        }
        uint4* o = (uint4*)wtb;
        o[i * 64 + lane] = make_uint4(u[0], u[1], u[2], u[3]);
    }
}

// transpose features (B,V,C,H,W) f32 -> channel-last bf16 (B,V,H,W,C): 64 B/pixel
__global__ __launch_bounds__(256) void transpose_kernel(const float* __restrict__ feat,
                                                        unsigned* __restrict__ feat_cl) {
    int idx = blockIdx.x * 256 + threadIdx.x;  // over B*V*HW
    if (idx >= B_ * V_ * HW_) return;
    int pix = idx % HW_;
    int bv = idx / HW_;
    const float* src = feat + (size_t)bv * C_ * HW_ + pix;
    unsigned u[16];
#pragma unroll
    for (int j = 0; j < 16; ++j) {
        float a = src[(size_t)(2 * j) * HW_];
        float b = src[(size_t)(2 * j + 1) * HW_];
        u[j] = bf_rne(a) | (bf_rne(b) << 16);
    }
    uint4* dst = (uint4*)(feat_cl + (size_t)idx * 16);
    dst[0] = make_uint4(u[0], u[1], u[2], u[3]);
    dst[1] = make_uint4(u[4], u[5], u[6], u[7]);
    dst[2] = make_uint4(u[8], u[9], u[10], u[11]);
    dst[3] = make_uint4(u[12], u[13], u[14], u[15]);
}

// Fused homography warp + bilinear + variance + conv channel-reduction + kw-fold.
// Block = 640 threads = one (b,d,h) row: 160 voxels x 4 channel-quarter lanes.
// Features are bf16 channel-last: one 16B load = one corner's 8 channels, so a
// lane quad covers a full 64B pixel per corner with 4 packed loads. Lane cq of
// each quad computes the projection for view cq only; all 4 views' weights +
// byte offsets are broadcast up-front (quad shfl) so the 16 corner loads issue
// with no DS dependency in between. T-dot on MFMA; taps round-trip a row-local
// LDS tile and exit as 9 kw-folded U planes: [j9=kd*3+kh][b][d][h][w].
__global__ __launch_bounds__(640, 5) void warp_kernel(const unsigned char* __restrict__ fb,
                                                      const float* __restrict__ rt,
                                                      const float* __restrict__ dv,
                                                      const unsigned* __restrict__ wtb,
                                                      float* __restrict__ U) {
    __shared__ float lt[160 * 29];            // [voxel][tap], stride 29 (odd)
    const int tid = threadIdx.x;
    const int lane = tid & 63;
    const int cq = tid & 3;                   // channel quarter
    const int vxl = tid >> 2;                 // voxel (w coordinate) 0..159
    const int b = blockIdx.z;
    const int d = blockIdx.y;
    const int h = blockIdx.x;
    const float wf = (float)vxl, hf = (float)h;
    const float dep = dv[b * D_ + d];         // uniform -> s_load

    // A-fragments (bf16 conv weights), constant per lane
    const uint4* wp = (const uint4*)wtb;
    uint4 a0u = wp[lane];
    uint4 a1u = wp[64 + lane];

    // own view (cq): projection + bilinear weights + corner pixel indices
    float w00, w01, w10, w11;
    int pix00, pix01, pix10, pix11;
    {
        const float* m = rt + (b * (V_ - 1) + cq) * 12;
        float xp = fmaf(fmaf(m[0], wf, fmaf(m[1], hf, m[2])), dep, m[9]);
        float yp = fmaf(fmaf(m[3], wf, fmaf(m[4], hf, m[5])), dep, m[10]);
        float zp = fmaf(fmaf(m[6], wf, fmaf(m[7], hf, m[8])), dep, m[11]);
        float iz = __builtin_amdgcn_rcpf(zp);
        float ix = xp * iz, iy = yp * iz;
        float x0f = floorf(ix), y0f = floorf(iy);
        float wx1 = ix - x0f, wx0 = 1.f - wx1;
        float wy1 = iy - y0f, wy0 = 1.f - wy1;
        float x1f = x0f + 1.f, y1f = y0f + 1.f;
        bool vx0 = (x0f >= 0.f) && (x0f <= (float)(W_ - 1));
        bool vx1 = (x1f >= 0.f) && (x1f <= (float)(W_ - 1));
        bool vy0 = (y0f >= 0.f) && (y0f <= (float)(H_ - 1));
        bool vy1 = (y1f >= 0.f) && (y1f <= (float)(H_ - 1));
        int x0i = (int)fminf(fmaxf(x0f, 0.f), (float)(W_ - 1));
        int x1i = (int)fminf(fmaxf(x1f, 0.f), (float)(W_ - 1));
        int y0i = (int)fminf(fmaxf(y0f, 0.f), (float)(H_ - 1));
        int y1i = (int)fminf(fmaxf(y1f, 0.f), (float)(H_ - 1));
        w00 = wx0 * wy0 * ((vx0 && vy0) ? 1.f : 0.f);
        w01 = wx1 * wy0 * ((vx1 && vy0) ? 1.f : 0.f);
        w10 = wx0 * wy1 * ((vx0 && vy1) ? 1.f : 0.f);
        w11 = wx1 * wy1 * ((vx1 && vy1) ? 1.f : 0.f);
        pix00 = y0i * W_ + x0i;
        pix01 = y0i * W_ + x1i;
        pix10 = y1i * W_ + x0i;
        pix11 = y1i * W_ + x1i;
    }

    // broadcast all 4 views' weights + byte offsets up-front (quad-local shfl)
    float Wb[4][4];
    unsigned Ob[4][4];
#pragma unroll
    for (int v = 0; v < 4; ++v) {
        int sl = (lane & ~3) | v;
        Wb[v][0] = __shfl(w00, sl);
        Wb[v][1] = __shfl(w01, sl);
        Wb[v][2] = __shfl(w10, sl);
        Wb[v][3] = __shfl(w11, sl);
        Ob[v][0] = ((unsigned)__shfl(pix00, sl) << 6) + (cq << 4);
        Ob[v][1] = ((unsigned)__shfl(pix01, sl) << 6) + (cq << 4);
        Ob[v][2] = ((unsigned)__shfl(pix10, sl) << 6) + (cq << 4);
        Ob[v][3] = ((unsigned)__shfl(pix11, sl) << 6) + (cq << 4);
    }

    // ref view: own pixel, own 8 channels
    float s[8], q[8];
    {
        const unsigned char* rb = fb + (size_t)(b * V_) * HW_ * 64;
        uint4 r = *(const uint4*)(rb + (((unsigned)(h * W_ + vxl)) << 6) + (cq << 4));
        float f[8];
        unpack8(r, f);
#pragma unroll
        for (int j = 0; j < 8; ++j) { s[j] = f[j]; q[j] = f[j] * f[j]; }
    }

#pragma unroll
    for (int v = 0; v < 4; ++v) {
        const unsigned char* base = fb + (size_t)(b * V_ + v + 1) * HW_ * 64;
        uint4 c0 = *(const uint4*)(base + Ob[v][0]);
        uint4 c1 = *(const uint4*)(base + Ob[v][1]);
        uint4 c2 = *(const uint4*)(base + Ob[v][2]);
        uint4 c3 = *(const uint4*)(base + Ob[v][3]);
        float f0[8], f1[8], f2[8], f3[8];
        unpack8(c0, f0);
        unpack8(c1, f1);
        unpack8(c2, f2);
        unpack8(c3, f3);
        float W00 = Wb[v][0], W01 = Wb[v][1], W10 = Wb[v][2], W11 = Wb[v][3];
#pragma unroll
        for (int j = 0; j < 8; ++j) {
            float a = fmaf(f0[j], W00, fmaf(f1[j], W01, fmaf(f2[j], W10, f3[j] * W11)));
            s[j] += a;
            q[j] = fmaf(a, a, q[j]);
        }
    }

    // variance for this thread's 8 channels, packed to bf16
    const float invV = 1.0f / (float)V_;
    unsigned pk[4];
#pragma unroll
    for (int jj = 0; jj < 4; ++jj) {
        float m0 = s[2 * jj] * invV, m1 = s[2 * jj + 1] * invV;
        float v0 = fmaf(-m0, m0, q[2 * jj] * invV);
        float v1 = fmaf(-m1, m1, q[2 * jj + 1] * invV);
        pk[jj] = bf_rne(v0) | (bf_rne(v1) << 16);
    }

    // permute to B-fragment layout: target lane L gets (voxel L&15, quarter L>>4)
    // which lives in source lane (L&15)*4 + (L>>4)
    uint4 bu;
    {
        int srcl = ((lane & 15) << 2) + (lane >> 4);
        bu.x = (unsigned)__shfl((int)pk[0], srcl);
        bu.y = (unsigned)__shfl((int)pk[1], srcl);
        bu.z = (unsigned)__shfl((int)pk[2], srcl);
        bu.w = (unsigned)__shfl((int)pk[3], srcl);
    }
    short8 bfrag = __builtin_bit_cast(short8, bu);
    short8 afrag0 = __builtin_bit_cast(short8, a0u);
    short8 afrag1 = __builtin_bit_cast(short8, a1u);

    floatx4 z = {0.f, 0.f, 0.f, 0.f};
    // D[m=tap][n=voxel-in-wave]; lane L: col=L&15, rows=(L>>4)*4+r
    floatx4 t0 = __builtin_amdgcn_mfma_f32_16x16x32_bf16(afrag0, bfrag, z, 0, 0, 0);
    floatx4 t1 = __builtin_amdgcn_mfma_f32_16x16x32_bf16(afrag1, bfrag, z, 0, 0, 0);

    // scatter taps to the row-local LDS tile
    {
        int vx = ((tid >> 6) << 4) + (lane & 15);   // wave*16 + col
        int tq = (lane >> 4) << 2;
        float* lp = &lt[vx * 29 + tq];
#pragma unroll
        for (int r = 0; r < 4; ++r) {
            lp[r] = t0[r];
            if (tq + r < 11) lp[16 + r] = t1[r];     // taps 16..26
        }
    }
    __syncthreads();

    // kw-fold: U_{j9}[w] = T_{j9,0}[w-1] + T_{j9,1}[w] + T_{j9,2}[w+1]
    const unsigned rowbase = (unsigned)(b * PLANE + d * HW_ + h * W_);
#pragma unroll
    for (int u = tid; u < 9 * 160; u += 640) {
        int j9 = u / 160;
        int vox = u - j9 * 160;
        int base = vox * 29 + j9 * 3;
        float a = lt[base + 1];
        if (vox > 0)   a += lt[base - 29];
        if (vox < 159) a += lt[base + 29 + 2];
        U[(unsigned)(j9 * NVOX) + rowbase + vox] = a;
    }
}

// Fused cost + softmax/depth/conf/itg. Thread = (b, pixel); streams dd over the
// 9 U planes accumulating cost[48] in registers:
//   cost[d] = sum_kd V_kd[d+kd-1],  V_kd[dd] = sum_kh U[3kd+kh][dd, h+kh-1, w]
__global__ __launch_bounds__(64) void costout_kernel(const float* __restrict__ U,
                                                     const float* __restrict__ dv,
                                                     float* __restrict__ out) {
    int tid = blockIdx.x * 64 + threadIdx.x;   // over B*HW
    if (tid >= B_ * HW_) return;
    int pix = tid % HW_;
    int b = tid / HW_;
    int h = pix / W_;
    const unsigned gbase = (unsigned)(b * PLANE + pix);
    const bool ok0 = (h > 0), ok2 = (h < H_ - 1);

    float cost[D_];
#pragma unroll
    for (int d0 = 0; d0 < D_; ++d0) cost[d0] = 0.f;

#pragma unroll
    for (int dd = 0; dd < D_; ++dd) {
        float v0 = 0.f, v1 = 0.f, v2 = 0.f;
        unsigned o1 = gbase + (unsigned)(dd * HW_);
#pragma unroll
        for (int kh = 0; kh < 3; ++kh) {
            if (kh == 0 && !ok0) continue;
            if (kh == 2 && !ok2) continue;
            unsigned o = o1 + (unsigned)((kh - 1) * W_);
            v0 += U[(unsigned)((0 * 3 + kh) * NVOX) + o];
            v1 += U[(unsigned)((1 * 3 + kh) * NVOX) + o];
            v2 += U[(unsigned)((2 * 3 + kh) * NVOX) + o];
        }
        if (dd + 1 < D_) cost[dd + 1] += v0;
        cost[dd] += v1;
        if (dd >= 1) cost[dd - 1] += v2;
    }

    float mx = -1e30f;
#pragma unroll
    for (int d0 = 0; d0 < D_; ++d0) mx = fmaxf(mx, cost[d0]);
    float S = 0.f;
#pragma unroll
    for (int d0 = 0; d0 < D_; ++d0) {
        cost[d0] = expf(cost[d0] - mx);
        S += cost[d0];
    }
    float invS = 1.f / S;
    float S2 = 0.f;
#pragma unroll
    for (int d0 = 0; d0 < D_; ++d0) {
        cost[d0] *= invS;          // prob
        S2 += cost[d0];
    }
    float invS2 = 1.f / fmaxf(S2, 1e-12f);
    float depth = 0.f, dif = 0.f;
#pragma unroll
    for (int d0 = 0; d0 < D_; ++d0) {
        depth = fmaf(cost[d0] * invS2, dv[b * D_ + d0], depth);
        dif = fmaf(cost[d0], (float)d0, dif);
    }
    int di = (int)dif;
    di = min(max(di, 0), D_ - 1);
    float conf = 0.f;
#pragma unroll
    for (int d0 = 0; d0 < D_; ++d0) {
        if (d0 >= di - 1 && d0 <= di + 2) conf += cost[d0];
    }
    out[tid] = depth;
    out[B_ * HW_ + tid] = conf;
    float* itg = out + 2 * B_ * HW_ + (size_t)b * PLANE + pix;
#pragma unroll
    for (int d0 = 0; d0 < D_; ++d0) itg[(size_t)d0 * HW_] = cost[d0] * invS2;
}

extern "C" void kernel_launch(void* const* d_in, const int* in_sizes, int n_in,
                              void* d_out, int out_size, void* d_ws, size_t ws_size,
                              hipStream_t stream) {
    const float* feat = (const float*)d_in[0];   // (B,V,C,H,W)
    const float* proj = (const float*)d_in[1];   // (B,V,2,4,4)
    const float* dv   = (const float*)d_in[2];   // (B,D)
    const float* wreg = (const float*)d_in[3];   // (1,C,3,3,3)
    float* out = (float*)d_out;
    float* ws = (float*)d_ws;

    // workspace layout (floats)
    const size_t rt_off = 0;
    const size_t rt_sz = 128;
    const size_t wtb_off = rt_off + rt_sz;
    const size_t wtb_sz = 512;                            // 2*64*4 uints
    const size_t fcl_off = wtb_off + wtb_sz;
    const size_t fcl_sz = (size_t)B_ * V_ * HW_ * 16;     // bf16 pixels: 16 uints each
    const size_t U_off = fcl_off + fcl_sz;
    const size_t U_sz = (size_t)9 * NVOX;                 // 17,694,720
    const size_t need = (U_off + U_sz) * sizeof(float);
    if (ws_size < need) return;  // workspace too small — fail loudly

    float* rt = ws + rt_off;
    unsigned* wtb = (unsigned*)(ws + wtb_off);
    unsigned* feat_cl = (unsigned*)(ws + fcl_off);
    float* U = ws + U_off;

    setup_kernel<<<1, 128, 0, stream>>>(proj, wreg, rt, wtb);
    transpose_kernel<<<(B_ * V_ * HW_) / 256, 256, 0, stream>>>(feat, feat_cl);
    dim3 wgrid(H_, D_, B_);
    warp_kernel<<<wgrid, 640, 0, stream>>>((const unsigned char*)feat_cl, rt, dv, wtb, U);
    costout_kernel<<<(B_ * HW_) / 64, 64, 0, stream>>>(U, dv, out);
}

// Round 7
// 299.659 us; speedup vs baseline: 2.0293x; 2.0293x over previous
//
#include <hip/hip_runtime.h>
#include <math.h>

// Problem constants (from setup_inputs): B,V,C,D,H,W = 2,5,32,48,128,160
constexpr int B_ = 2;
constexpr int V_ = 5;
constexpr int C_ = 32;
constexpr int D_ = 48;
constexpr int H_ = 128;
constexpr int W_ = 160;
constexpr int HW_ = H_ * W_;               // 20480
constexpr int NVOX = B_ * D_ * HW_;        // 1,966,080
constexpr int PLANE = D_ * HW_;            // 983,040 (per-batch voxels)

typedef short short8 __attribute__((ext_vector_type(8)));
typedef float floatx4 __attribute__((ext_vector_type(4)));

// ---------------- small matrix helpers (device) ----------------

__device__ inline void combine4(const float* pm, float out[4][4]) {
    const float* E = pm;
    const float* K = pm + 16;
    for (int i = 0; i < 3; ++i)
        for (int j = 0; j < 4; ++j) {
            float a = 0.f;
            for (int k = 0; k < 3; ++k) a += K[i * 4 + k] * E[k * 4 + j];
            out[i][j] = a;
        }
    for (int j = 0; j < 4; ++j) out[3][j] = E[12 + j];
}

__device__ inline void invert4(const float A[4][4], float inv[4][4]) {
    float M[4][8];
    for (int i = 0; i < 4; ++i)
        for (int j = 0; j < 4; ++j) {
            M[i][j] = A[i][j];
            M[i][4 + j] = (i == j) ? 1.f : 0.f;
        }
    for (int col = 0; col < 4; ++col) {
        int piv = col;
        float best = fabsf(M[col][col]);
        for (int r = col + 1; r < 4; ++r) {
            float v = fabsf(M[r][col]);
            if (v > best) { best = v; piv = r; }
        }
        if (piv != col)
            for (int j = 0; j < 8; ++j) { float t = M[col][j]; M[col][j] = M[piv][j]; M[piv][j] = t; }
        float ip = 1.f / M[col][col];
        for (int j = 0; j < 8; ++j) M[col][j] *= ip;
        for (int r = 0; r < 4; ++r) {
            if (r == col) continue;
            float f = M[r][col];
            for (int j = 0; j < 8; ++j) M[r][j] -= f * M[col][j];
        }
    }
    for (int i = 0; i < 4; ++i)
        for (int j = 0; j < 4; ++j) inv[i][j] = M[i][4 + j];
}

__device__ inline unsigned bf_rne(float f) {
    unsigned u = __float_as_uint(f);
    return (u + 0x7FFFu + ((u >> 16) & 1u)) >> 16;   // RNE (values are finite)
}

// setup: (a) per b,v: P = src_proj @ inv(ref_proj) -> rt[12 floats]
//        (b) prepack conv weights as bf16 MFMA A-fragments:
//            A[m=tap=lane&15 (+16i)][k=ch=(lane>>4)*8+j], taps>=27 zero-padded
__global__ void setup_kernel(const float* __restrict__ proj, const float* __restrict__ wreg,
                             float* __restrict__ rt, unsigned* __restrict__ wtb) {
    int t = threadIdx.x;
    if (t < B_) {
        int b = t;
        float ref[4][4], inv[4][4];
        combine4(proj + (size_t)((b * V_ + 0) * 2) * 16, ref);
        invert4(ref, inv);
        for (int v = 1; v < V_; ++v) {
            float src[4][4];
            combine4(proj + (size_t)((b * V_ + v) * 2) * 16, src);
            float P[3][4];
            for (int i = 0; i < 3; ++i)
                for (int j = 0; j < 4; ++j) {
                    float a = 0.f;
                    for (int k = 0; k < 4; ++k) a += src[i][k] * inv[k][j];
                    P[i][j] = a;
                }
            float* o = rt + (size_t)(b * (V_ - 1) + (v - 1)) * 12;
            o[0] = P[0][0]; o[1] = P[0][1]; o[2] = P[0][2];
            o[3] = P[1][0]; o[4] = P[1][1]; o[5] = P[1][2];
            o[6] = P[2][0]; o[7] = P[2][1]; o[8] = P[2][2];
            o[9] = P[0][3]; o[10] = P[1][3]; o[11] = P[2][3];
        }
    }
    if (t < 128) {
        int i = t >> 6;          // which mfma (taps 0-15 / 16-31)
        int lane = t & 63;
        int q = lane >> 4;
        int l = lane & 15;
        int tap = i * 16 + l;
        unsigned u[4];
#pragma unroll
        for (int jj = 0; jj < 4; ++jj) {
            int ch0 = q * 8 + 2 * jj;
            float v0 = (tap < 27) ? wreg[ch0 * 27 + tap] : 0.f;
            float v1 = (tap < 27) ? wreg[(ch0 + 1) * 27 + tap] : 0.f;
            u[jj] = bf_rne(v0) | (bf_rne(v1) << 16);
        }
        uint4* o = (uint4*)wtb;
        o[i * 64 + lane] = make_uint4(u[0], u[1], u[2], u[3]);
    }
}

// transpose features (B,V,C,H,W) f32 -> channel-last bf16 (B,V,H,W,C): 64 B/pixel
__global__ __launch_bounds__(256) void transpose_kernel(const float* __restrict__ feat,
                                                        unsigned* __restrict__ feat_cl) {
    int idx = blockIdx.x * 256 + threadIdx.x;  // over B*V*HW
    if (idx >= B_ * V_ * HW_) return;
    int pix = idx % HW_;
    int bv = idx / HW_;
    const float* src = feat + (size_t)bv * C_ * HW_ + pix;
    unsigned u[16];
#pragma unroll
    for (int j = 0; j < 16; ++j) {
        float a = src[(size_t)(2 * j) * HW_];
        float b = src[(size_t)(2 * j + 1) * HW_];
        u[j] = bf_rne(a) | (bf_rne(b) << 16);
    }
    uint4* dst = (uint4*)(feat_cl + (size_t)idx * 16);
    dst[0] = make_uint4(u[0], u[1], u[2], u[3]);
    dst[1] = make_uint4(u[4], u[5], u[6], u[7]);
    dst[2] = make_uint4(u[8], u[9], u[10], u[11]);
    dst[3] = make_uint4(u[12], u[13], u[14], u[15]);
}

// Fused homography warp + bilinear + variance + conv channel-reduction + kw-fold.
// Block = 640 threads = one (b,d,h) row: 160 voxels x 4 channel-quarter lanes.
// Features are bf16 channel-last: one 16B load covers a corner's 8 channels.
// Lane cq of each quad computes the projection for view cq only; weights +
// offsets broadcast per view inside the loop (keeps the live set small — the
// R6 up-front variant spilled to scratch: 1.14 GB writes). T-dot on MFMA; taps
// round-trip a row-local LDS tile, exit as 9 kw-folded U planes:
// U layout: [j9=kd*3+kh][b][d][h][w].
__global__ __launch_bounds__(640) void warp_kernel(const unsigned char* __restrict__ fb,
                                                   const float* __restrict__ rt,
                                                   const float* __restrict__ dv,
                                                   const unsigned* __restrict__ wtb,
                                                   float* __restrict__ U) {
    __shared__ float lt[160 * 29];            // [voxel][tap], stride 29 (odd)
    const int tid = threadIdx.x;
    const int lane = tid & 63;
    const int cq = tid & 3;                   // channel quarter
    const int vxl = tid >> 2;                 // voxel (w coordinate) 0..159
    const int b = blockIdx.z;
    const int d = blockIdx.y;
    const int h = blockIdx.x;
    const float wf = (float)vxl, hf = (float)h;
    const float dep = dv[b * D_ + d];         // uniform -> s_load

    // A-fragments (bf16 conv weights), constant per lane
    const uint4* wp = (const uint4*)wtb;
    uint4 a0u = wp[lane];
    uint4 a1u = wp[64 + lane];

    // own view (cq): projection + bilinear weights + corner pixel indices
    float w00, w01, w10, w11;
    int pix00, pix01, pix10, pix11;
    {
        const float* m = rt + (b * (V_ - 1) + cq) * 12;
        float xp = fmaf(fmaf(m[0], wf, fmaf(m[1], hf, m[2])), dep, m[9]);
        float yp = fmaf(fmaf(m[3], wf, fmaf(m[4], hf, m[5])), dep, m[10]);
        float zp = fmaf(fmaf(m[6], wf, fmaf(m[7], hf, m[8])), dep, m[11]);
        float iz = __builtin_amdgcn_rcpf(zp);
        float ix = xp * iz, iy = yp * iz;
        float x0f = floorf(ix), y0f = floorf(iy);
        float wx1 = ix - x0f, wx0 = 1.f - wx1;
        float wy1 = iy - y0f, wy0 = 1.f - wy1;
        float x1f = x0f + 1.f, y1f = y0f + 1.f;
        bool vx0 = (x0f >= 0.f) && (x0f <= (float)(W_ - 1));
        bool vx1 = (x1f >= 0.f) && (x1f <= (float)(W_ - 1));
        bool vy0 = (y0f >= 0.f) && (y0f <= (float)(H_ - 1));
        bool vy1 = (y1f >= 0.f) && (y1f <= (float)(H_ - 1));
        int x0i = (int)fminf(fmaxf(x0f, 0.f), (float)(W_ - 1));
        int x1i = (int)fminf(fmaxf(x1f, 0.f), (float)(W_ - 1));
        int y0i = (int)fminf(fmaxf(y0f, 0.f), (float)(H_ - 1));
        int y1i = (int)fminf(fmaxf(y1f, 0.f), (float)(H_ - 1));
        w00 = wx0 * wy0 * ((vx0 && vy0) ? 1.f : 0.f);
        w01 = wx1 * wy0 * ((vx1 && vy0) ? 1.f : 0.f);
        w10 = wx0 * wy1 * ((vx0 && vy1) ? 1.f : 0.f);
        w11 = wx1 * wy1 * ((vx1 && vy1) ? 1.f : 0.f);
        pix00 = y0i * W_ + x0i;
        pix01 = y0i * W_ + x1i;
        pix10 = y1i * W_ + x0i;
        pix11 = y1i * W_ + x1i;
    }

    // ref view: own pixel, own 8 channels (bf16x8 = one 16B load)
    float s[8], q[8];
    {
        const unsigned char* rb = fb + (size_t)(b * V_) * HW_ * 64;
        uint4 r = *(const uint4*)(rb + (((unsigned)(h * W_ + vxl)) << 6) + (cq << 4));
        float f0 = __uint_as_float(r.x << 16);
        float f1 = __uint_as_float(r.x & 0xffff0000u);
        float f2 = __uint_as_float(r.y << 16);
        float f3 = __uint_as_float(r.y & 0xffff0000u);
        float f4 = __uint_as_float(r.z << 16);
        float f5 = __uint_as_float(r.z & 0xffff0000u);
        float f6 = __uint_as_float(r.w << 16);
        float f7 = __uint_as_float(r.w & 0xffff0000u);
        s[0] = f0; s[1] = f1; s[2] = f2; s[3] = f3;
        s[4] = f4; s[5] = f5; s[6] = f6; s[7] = f7;
        q[0] = f0 * f0; q[1] = f1 * f1; q[2] = f2 * f2; q[3] = f3 * f3;
        q[4] = f4 * f4; q[5] = f5 * f5; q[6] = f6 * f6; q[7] = f7 * f7;
    }

#pragma unroll
    for (int v = 0; v < V_ - 1; ++v) {
        int sl = (lane & ~3) | v;             // quad-local broadcast source
        float W00 = __shfl(w00, sl), W01 = __shfl(w01, sl);
        float W10 = __shfl(w10, sl), W11 = __shfl(w11, sl);
        unsigned O00 = ((unsigned)__shfl(pix00, sl) << 6) + (cq << 4);
        unsigned O01 = ((unsigned)__shfl(pix01, sl) << 6) + (cq << 4);
        unsigned O10 = ((unsigned)__shfl(pix10, sl) << 6) + (cq << 4);
        unsigned O11 = ((unsigned)__shfl(pix11, sl) << 6) + (cq << 4);
        const unsigned char* base = fb + (size_t)(b * V_ + v + 1) * HW_ * 64;
        uint4 c0 = *(const uint4*)(base + O00);
        uint4 c1 = *(const uint4*)(base + O01);
        uint4 c2 = *(const uint4*)(base + O10);
        uint4 c3 = *(const uint4*)(base + O11);
        unsigned u0[4] = {c0.x, c0.y, c0.z, c0.w};
        unsigned u1[4] = {c1.x, c1.y, c1.z, c1.w};
        unsigned u2[4] = {c2.x, c2.y, c2.z, c2.w};
        unsigned u3[4] = {c3.x, c3.y, c3.z, c3.w};
#pragma unroll
        for (int jj = 0; jj < 4; ++jj) {
            float a0 = __uint_as_float(u0[jj] << 16);
            float b0 = __uint_as_float(u1[jj] << 16);
            float g0 = __uint_as_float(u2[jj] << 16);
            float d0 = __uint_as_float(u3[jj] << 16);
            float acc = fmaf(a0, W00, fmaf(b0, W01, fmaf(g0, W10, d0 * W11)));
            s[2 * jj] += acc;
            q[2 * jj] = fmaf(acc, acc, q[2 * jj]);
            float a1 = __uint_as_float(u0[jj] & 0xffff0000u);
            float b1 = __uint_as_float(u1[jj] & 0xffff0000u);
            float g1 = __uint_as_float(u2[jj] & 0xffff0000u);
            float d1 = __uint_as_float(u3[jj] & 0xffff0000u);
            float acc1 = fmaf(a1, W00, fmaf(b1, W01, fmaf(g1, W10, d1 * W11)));
            s[2 * jj + 1] += acc1;
            q[2 * jj + 1] = fmaf(acc1, acc1, q[2 * jj + 1]);
        }
    }

    // variance for this thread's 8 channels, packed to bf16
    const float invV = 1.0f / (float)V_;
    unsigned pk[4];
#pragma unroll
    for (int jj = 0; jj < 4; ++jj) {
        float m0 = s[2 * jj] * invV, m1 = s[2 * jj + 1] * invV;
        float v0 = fmaf(-m0, m0, q[2 * jj] * invV);
        float v1 = fmaf(-m1, m1, q[2 * jj + 1] * invV);
        pk[jj] = bf_rne(v0) | (bf_rne(v1) << 16);
    }

    // permute to B-fragment layout: target lane L gets (voxel L&15, quarter L>>4)
    // which lives in source lane (L&15)*4 + (L>>4)
    uint4 bu;
    {
        int srcl = ((lane & 15) << 2) + (lane >> 4);
        bu.x = (unsigned)__shfl((int)pk[0], srcl);
        bu.y = (unsigned)__shfl((int)pk[1], srcl);
        bu.z = (unsigned)__shfl((int)pk[2], srcl);
        bu.w = (unsigned)__shfl((int)pk[3], srcl);
    }
    short8 bfrag = __builtin_bit_cast(short8, bu);
    short8 afrag0 = __builtin_bit_cast(short8, a0u);
    short8 afrag1 = __builtin_bit_cast(short8, a1u);

    floatx4 z = {0.f, 0.f, 0.f, 0.f};
    // D[m=tap][n=voxel-in-wave]; lane L: col=L&15, rows=(L>>4)*4+r
    floatx4 t0 = __builtin_amdgcn_mfma_f32_16x16x32_bf16(afrag0, bfrag, z, 0, 0, 0);
    floatx4 t1 = __builtin_amdgcn_mfma_f32_16x16x32_bf16(afrag1, bfrag, z, 0, 0, 0);

    // scatter taps to the row-local LDS tile
    {
        int vx = ((tid >> 6) << 4) + (lane & 15);   // wave*16 + col
        int tq = (lane >> 4) << 2;
        float* lp = &lt[vx * 29 + tq];
#pragma unroll
        for (int r = 0; r < 4; ++r) {
            lp[r] = t0[r];
            if (tq + r < 11) lp[16 + r] = t1[r];     // taps 16..26
        }
    }
    __syncthreads();

    // kw-fold: U_{j9}[w] = T_{j9,0}[w-1] + T_{j9,1}[w] + T_{j9,2}[w+1]
    const unsigned rowbase = (unsigned)(b * PLANE + d * HW_ + h * W_);
#pragma unroll
    for (int u = tid; u < 9 * 160; u += 640) {
        int j9 = u / 160;
        int vox = u - j9 * 160;
        int base = vox * 29 + j9 * 3;
        float a = lt[base + 1];
        if (vox > 0)   a += lt[base - 29];
        if (vox < 159) a += lt[base + 29 + 2];
        U[(unsigned)(j9 * NVOX) + rowbase + vox] = a;
    }
}

// Fused cost + softmax/depth/conf/itg. Thread = (b, pixel); streams dd over the
// 9 U planes accumulating cost[48] in registers:
//   cost[d] = sum_kd V_kd[d+kd-1],  V_kd[dd] = sum_kh U[3kd+kh][dd, h+kh-1, w]
__global__ __launch_bounds__(64) void costout_kernel(const float* __restrict__ U,
                                                     const float* __restrict__ dv,
                                                     float* __restrict__ out) {
    int tid = blockIdx.x * 64 + threadIdx.x;   // over B*HW
    if (tid >= B_ * HW_) return;
    int pix = tid % HW_;
    int b = tid / HW_;
    int h = pix / W_;
    const unsigned gbase = (unsigned)(b * PLANE + pix);
    const bool ok0 = (h > 0), ok2 = (h < H_ - 1);

    float cost[D_];
#pragma unroll
    for (int d0 = 0; d0 < D_; ++d0) cost[d0] = 0.f;

#pragma unroll
    for (int dd = 0; dd < D_; ++dd) {
        float v0 = 0.f, v1 = 0.f, v2 = 0.f;
        unsigned o1 = gbase + (unsigned)(dd * HW_);
#pragma unroll
        for (int kh = 0; kh < 3; ++kh) {
            if (kh == 0 && !ok0) continue;
            if (kh == 2 && !ok2) continue;
            unsigned o = o1 + (unsigned)((kh - 1) * W_);
            v0 += U[(unsigned)((0 * 3 + kh) * NVOX) + o];
            v1 += U[(unsigned)((1 * 3 + kh) * NVOX) + o];
            v2 += U[(unsigned)((2 * 3 + kh) * NVOX) + o];
        }
        if (dd + 1 < D_) cost[dd + 1] += v0;
        cost[dd] += v1;
        if (dd >= 1) cost[dd - 1] += v2;
    }

    float mx = -1e30f;
#pragma unroll
    for (int d0 = 0; d0 < D_; ++d0) mx = fmaxf(mx, cost[d0]);
    float S = 0.f;
#pragma unroll
    for (int d0 = 0; d0 < D_; ++d0) {
        cost[d0] = expf(cost[d0] - mx);
        S += cost[d0];
    }
    float invS = 1.f / S;
    float S2 = 0.f;
#pragma unroll
    for (int d0 = 0; d0 < D_; ++d0) {
        cost[d0] *= invS;          // prob
        S2 += cost[d0];
    }
    float invS2 = 1.f / fmaxf(S2, 1e-12f);
    float depth = 0.f, dif = 0.f;
#pragma unroll
    for (int d0 = 0; d0 < D_; ++d0) {
        depth = fmaf(cost[d0] * invS2, dv[b * D_ + d0], depth);
        dif = fmaf(cost[d0], (float)d0, dif);
    }
    int di = (int)dif;
    di = min(max(di, 0), D_ - 1);
    float conf = 0.f;
#pragma unroll
    for (int d0 = 0; d0 < D_; ++d0) {
        if (d0 >= di - 1 && d0 <= di + 2) conf += cost[d0];
    }
    out[tid] = depth;
    out[B_ * HW_ + tid] = conf;
    float* itg = out + 2 * B_ * HW_ + (size_t)b * PLANE + pix;
#pragma unroll
    for (int d0 = 0; d0 < D_; ++d0) itg[(size_t)d0 * HW_] = cost[d0] * invS2;
}

extern "C" void kernel_launch(void* const* d_in, const int* in_sizes, int n_in,
                              void* d_out, int out_size, void* d_ws, size_t ws_size,
                              hipStream_t stream) {
    const float* feat = (const float*)d_in[0];   // (B,V,C,H,W)
    const float* proj = (const float*)d_in[1];   // (B,V,2,4,4)
    const float* dv   = (const float*)d_in[2];   // (B,D)
    const float* wreg = (const float*)d_in[3];   // (1,C,3,3,3)
    float* out = (float*)d_out;
    float* ws = (float*)d_ws;

    // workspace layout (floats)
    const size_t rt_off = 0;
    const size_t rt_sz = 128;
    const size_t wtb_off = rt_off + rt_sz;
    const size_t wtb_sz = 512;                            // 2*64*4 uints
    const size_t fcl_off = wtb_off + wtb_sz;
    const size_t fcl_sz = (size_t)B_ * V_ * HW_ * 16;     // bf16 pixels: 16 uints each
    const size_t U_off = fcl_off + fcl_sz;
    const size_t U_sz = (size_t)9 * NVOX;                 // 17,694,720
    const size_t need = (U_off + U_sz) * sizeof(float);
    if (ws_size < need) return;  // workspace too small — fail loudly

    float* rt = ws + rt_off;
    unsigned* wtb = (unsigned*)(ws + wtb_off);
    unsigned* feat_cl = (unsigned*)(ws + fcl_off);
    float* U = ws + U_off;

    setup_kernel<<<1, 128, 0, stream>>>(proj, wreg, rt, wtb);
    transpose_kernel<<<(B_ * V_ * HW_) / 256, 256, 0, stream>>>(feat, feat_cl);
    dim3 wgrid(H_, D_, B_);
    warp_kernel<<<wgrid, 640, 0, stream>>>((const unsigned char*)feat_cl, rt, dv, wtb, U);
    costout_kernel<<<(B_ * HW_) / 64, 64, 0, stream>>>(U, dv, out);
}

// Round 8
// 248.807 us; speedup vs baseline: 2.4440x; 1.2044x over previous
//
#include <hip/hip_runtime.h>
#include <math.h>

// Problem constants (from setup_inputs): B,V,C,D,H,W = 2,5,32,48,128,160
constexpr int B_ = 2;
constexpr int V_ = 5;
constexpr int C_ = 32;
constexpr int D_ = 48;
constexpr int H_ = 128;
constexpr int W_ = 160;
constexpr int HW_ = H_ * W_;               // 20480
constexpr int NVOX = B_ * D_ * HW_;        // 1,966,080
constexpr int PLANE = D_ * HW_;            // 983,040 (per-batch voxels)

typedef short short8 __attribute__((ext_vector_type(8)));
typedef float floatx4 __attribute__((ext_vector_type(4)));

// ---------------- small matrix helpers (device) ----------------

__device__ inline void combine4(const float* pm, float out[4][4]) {
    const float* E = pm;
    const float* K = pm + 16;
    for (int i = 0; i < 3; ++i)
        for (int j = 0; j < 4; ++j) {
            float a = 0.f;
            for (int k = 0; k < 3; ++k) a += K[i * 4 + k] * E[k * 4 + j];
            out[i][j] = a;
        }
    for (int j = 0; j < 4; ++j) out[3][j] = E[12 + j];
}

__device__ inline void invert4(const float A[4][4], float inv[4][4]) {
    float M[4][8];
    for (int i = 0; i < 4; ++i)
        for (int j = 0; j < 4; ++j) {
            M[i][j] = A[i][j];
            M[i][4 + j] = (i == j) ? 1.f : 0.f;
        }
    for (int col = 0; col < 4; ++col) {
        int piv = col;
        float best = fabsf(M[col][col]);
        for (int r = col + 1; r < 4; ++r) {
            float v = fabsf(M[r][col]);
            if (v > best) { best = v; piv = r; }
        }
        if (piv != col)
            for (int j = 0; j < 8; ++j) { float t = M[col][j]; M[col][j] = M[piv][j]; M[piv][j] = t; }
        float ip = 1.f / M[col][col];
        for (int j = 0; j < 8; ++j) M[col][j] *= ip;
        for (int r = 0; r < 4; ++r) {
            if (r == col) continue;
            float f = M[r][col];
            for (int j = 0; j < 8; ++j) M[r][j] -= f * M[col][j];
        }
    }
    for (int i = 0; i < 4; ++i)
        for (int j = 0; j < 4; ++j) inv[i][j] = M[i][4 + j];
}

__device__ inline unsigned bf_rne(float f) {
    unsigned u = __float_as_uint(f);
    return (u + 0x7FFFu + ((u >> 16) & 1u)) >> 16;   // RNE (values are finite)
}

// setup: (a) per b,v: P = src_proj @ inv(ref_proj) -> rt[12 floats]
//        (b) prepack conv weights as bf16 MFMA A-fragments:
//            A[m=tap=lane&15 (+16i)][k=ch=(lane>>4)*8+j], taps>=27 zero-padded
__global__ void setup_kernel(const float* __restrict__ proj, const float* __restrict__ wreg,
                             float* __restrict__ rt, unsigned* __restrict__ wtb) {
    int t = threadIdx.x;
    if (t < B_) {
        int b = t;
        float ref[4][4], inv[4][4];
        combine4(proj + (size_t)((b * V_ + 0) * 2) * 16, ref);
        invert4(ref, inv);
        for (int v = 1; v < V_; ++v) {
            float src[4][4];
            combine4(proj + (size_t)((b * V_ + v) * 2) * 16, src);
            float P[3][4];
            for (int i = 0; i < 3; ++i)
                for (int j = 0; j < 4; ++j) {
                    float a = 0.f;
                    for (int k = 0; k < 4; ++k) a += src[i][k] * inv[k][j];
                    P[i][j] = a;
                }
            float* o = rt + (size_t)(b * (V_ - 1) + (v - 1)) * 12;
            o[0] = P[0][0]; o[1] = P[0][1]; o[2] = P[0][2];
            o[3] = P[1][0]; o[4] = P[1][1]; o[5] = P[1][2];
            o[6] = P[2][0]; o[7] = P[2][1]; o[8] = P[2][2];
            o[9] = P[0][3]; o[10] = P[1][3]; o[11] = P[2][3];
        }
    }
    if (t < 128) {
        int i = t >> 6;          // which mfma (taps 0-15 / 16-31)
        int lane = t & 63;
        int q = lane >> 4;
        int l = lane & 15;
        int tap = i * 16 + l;
        unsigned u[4];
#pragma unroll
        for (int jj = 0; jj < 4; ++jj) {
            int ch0 = q * 8 + 2 * jj;
            float v0 = (tap < 27) ? wreg[ch0 * 27 + tap] : 0.f;
            float v1 = (tap < 27) ? wreg[(ch0 + 1) * 27 + tap] : 0.f;
            u[jj] = bf_rne(v0) | (bf_rne(v1) << 16);
        }
        uint4* o = (uint4*)wtb;
        o[i * 64 + lane] = make_uint4(u[0], u[1], u[2], u[3]);
    }
}

// transpose features (B,V,C,H,W) f32 -> channel-last bf16 (B,V,H,W,C): 64 B/pixel
__global__ __launch_bounds__(256) void transpose_kernel(const float* __restrict__ feat,
                                                        unsigned* __restrict__ feat_cl) {
    int idx = blockIdx.x * 256 + threadIdx.x;  // over B*V*HW
    if (idx >= B_ * V_ * HW_) return;
    int pix = idx % HW_;
    int bv = idx / HW_;
    const float* src = feat + (size_t)bv * C_ * HW_ + pix;
    unsigned u[16];
#pragma unroll
    for (int j = 0; j < 16; ++j) {
        float a = src[(size_t)(2 * j) * HW_];
        float b = src[(size_t)(2 * j + 1) * HW_];
        u[j] = bf_rne(a) | (bf_rne(b) << 16);
    }
    uint4* dst = (uint4*)(feat_cl + (size_t)idx * 16);
    dst[0] = make_uint4(u[0], u[1], u[2], u[3]);
    dst[1] = make_uint4(u[4], u[5], u[6], u[7]);
    dst[2] = make_uint4(u[8], u[9], u[10], u[11]);
    dst[3] = make_uint4(u[12], u[13], u[14], u[15]);
}

// Fused homography warp + bilinear + variance + conv channel-reduction.
// Block = 256 threads = 64 pixels x 4 channel-quarter lanes; grid (320, D, B)
// so b/d/depth are wave-uniform (SGPR). bf16 channel-last features: one 16B
// load covers a corner's 8 channels. Lane cq of each quad computes view cq's
// projection; weights+offsets broadcast per view via quad shfl (small live
// set — R6's up-front hoist spilled). T-dot on MFMA; 27 tap planes stored
// straight from MFMA regs (no LDS, no barrier — R7's fold version sat at 27%
// occupancy / 50% VALUBusy). T layout: [j=0..26][b][d][h][w].
__global__ __launch_bounds__(256) void warp_kernel(const unsigned char* __restrict__ fb,
                                                   const float* __restrict__ rt,
                                                   const float* __restrict__ dv,
                                                   const unsigned* __restrict__ wtb,
                                                   float* __restrict__ T) {
    const int tid = threadIdx.x;
    const int lane = tid & 63;
    const int cq = tid & 3;                   // channel quarter
    const int b = blockIdx.z;
    const int d = blockIdx.y;
    const int pixb = blockIdx.x * 64;         // block's first pixel
    const int pix = pixb + (tid >> 2);
    const int w = pix % W_;
    const int h = pix / W_;
    const float wf = (float)w, hf = (float)h;
    const float dep = dv[b * D_ + d];         // uniform -> s_load

    // A-fragments (bf16 conv weights), constant per lane
    const uint4* wp = (const uint4*)wtb;
    uint4 a0u = wp[lane];
    uint4 a1u = wp[64 + lane];

    // own view (cq): projection + bilinear weights + corner pixel indices
    float w00, w01, w10, w11;
    int pix00, pix01, pix10, pix11;
    {
        const float* m = rt + (b * (V_ - 1) + cq) * 12;
        float xp = fmaf(fmaf(m[0], wf, fmaf(m[1], hf, m[2])), dep, m[9]);
        float yp = fmaf(fmaf(m[3], wf, fmaf(m[4], hf, m[5])), dep, m[10]);
        float zp = fmaf(fmaf(m[6], wf, fmaf(m[7], hf, m[8])), dep, m[11]);
        float iz = __builtin_amdgcn_rcpf(zp);
        float ix = xp * iz, iy = yp * iz;
        float x0f = floorf(ix), y0f = floorf(iy);
        float wx1 = ix - x0f, wx0 = 1.f - wx1;
        float wy1 = iy - y0f, wy0 = 1.f - wy1;
        float x1f = x0f + 1.f, y1f = y0f + 1.f;
        bool vx0 = (x0f >= 0.f) && (x0f <= (float)(W_ - 1));
        bool vx1 = (x1f >= 0.f) && (x1f <= (float)(W_ - 1));
        bool vy0 = (y0f >= 0.f) && (y0f <= (float)(H_ - 1));
        bool vy1 = (y1f >= 0.f) && (y1f <= (float)(H_ - 1));
        int x0i = (int)fminf(fmaxf(x0f, 0.f), (float)(W_ - 1));
        int x1i = (int)fminf(fmaxf(x1f, 0.f), (float)(W_ - 1));
        int y0i = (int)fminf(fmaxf(y0f, 0.f), (float)(H_ - 1));
        int y1i = (int)fminf(fmaxf(y1f, 0.f), (float)(H_ - 1));
        w00 = wx0 * wy0 * ((vx0 && vy0) ? 1.f : 0.f);
        w01 = wx1 * wy0 * ((vx1 && vy0) ? 1.f : 0.f);
        w10 = wx0 * wy1 * ((vx0 && vy1) ? 1.f : 0.f);
        w11 = wx1 * wy1 * ((vx1 && vy1) ? 1.f : 0.f);
        pix00 = y0i * W_ + x0i;
        pix01 = y0i * W_ + x1i;
        pix10 = y1i * W_ + x0i;
        pix11 = y1i * W_ + x1i;
    }

    // ref view: own pixel, own 8 channels (bf16x8 = one 16B load)
    float s[8], q[8];
    {
        const unsigned char* rb = fb + (size_t)(b * V_) * HW_ * 64;
        uint4 r = *(const uint4*)(rb + (((unsigned)pix) << 6) + (cq << 4));
        float f0 = __uint_as_float(r.x << 16);
        float f1 = __uint_as_float(r.x & 0xffff0000u);
        float f2 = __uint_as_float(r.y << 16);
        float f3 = __uint_as_float(r.y & 0xffff0000u);
        float f4 = __uint_as_float(r.z << 16);
        float f5 = __uint_as_float(r.z & 0xffff0000u);
        float f6 = __uint_as_float(r.w << 16);
        float f7 = __uint_as_float(r.w & 0xffff0000u);
        s[0] = f0; s[1] = f1; s[2] = f2; s[3] = f3;
        s[4] = f4; s[5] = f5; s[6] = f6; s[7] = f7;
        q[0] = f0 * f0; q[1] = f1 * f1; q[2] = f2 * f2; q[3] = f3 * f3;
        q[4] = f4 * f4; q[5] = f5 * f5; q[6] = f6 * f6; q[7] = f7 * f7;
    }

#pragma unroll
    for (int v = 0; v < V_ - 1; ++v) {
        int sl = (lane & ~3) | v;             // quad-local broadcast source
        float W00 = __shfl(w00, sl), W01 = __shfl(w01, sl);
        float W10 = __shfl(w10, sl), W11 = __shfl(w11, sl);
        unsigned O00 = ((unsigned)__shfl(pix00, sl) << 6) + (cq << 4);
        unsigned O01 = ((unsigned)__shfl(pix01, sl) << 6) + (cq << 4);
        unsigned O10 = ((unsigned)__shfl(pix10, sl) << 6) + (cq << 4);
        unsigned O11 = ((unsigned)__shfl(pix11, sl) << 6) + (cq << 4);
        const unsigned char* base = fb + (size_t)(b * V_ + v + 1) * HW_ * 64;
        uint4 c0 = *(const uint4*)(base + O00);
        uint4 c1 = *(const uint4*)(base + O01);
        uint4 c2 = *(const uint4*)(base + O10);
        uint4 c3 = *(const uint4*)(base + O11);
        unsigned u0[4] = {c0.x, c0.y, c0.z, c0.w};
        unsigned u1[4] = {c1.x, c1.y, c1.z, c1.w};
        unsigned u2[4] = {c2.x, c2.y, c2.z, c2.w};
        unsigned u3[4] = {c3.x, c3.y, c3.z, c3.w};
#pragma unroll
        for (int jj = 0; jj < 4; ++jj) {
            float a0 = __uint_as_float(u0[jj] << 16);
            float b0 = __uint_as_float(u1[jj] << 16);
            float g0 = __uint_as_float(u2[jj] << 16);
            float d0 = __uint_as_float(u3[jj] << 16);
            float acc = fmaf(a0, W00, fmaf(b0, W01, fmaf(g0, W10, d0 * W11)));
            s[2 * jj] += acc;
            q[2 * jj] = fmaf(acc, acc, q[2 * jj]);
            float a1 = __uint_as_float(u0[jj] & 0xffff0000u);
            float b1 = __uint_as_float(u1[jj] & 0xffff0000u);
            float g1 = __uint_as_float(u2[jj] & 0xffff0000u);
            float d1 = __uint_as_float(u3[jj] & 0xffff0000u);
            float acc1 = fmaf(a1, W00, fmaf(b1, W01, fmaf(g1, W10, d1 * W11)));
            s[2 * jj + 1] += acc1;
            q[2 * jj + 1] = fmaf(acc1, acc1, q[2 * jj + 1]);
        }
    }

    // variance for this thread's 8 channels, packed to bf16
    const float invV = 1.0f / (float)V_;
    unsigned pk[4];
#pragma unroll
    for (int jj = 0; jj < 4; ++jj) {
        float m0 = s[2 * jj] * invV, m1 = s[2 * jj + 1] * invV;
        float v0 = fmaf(-m0, m0, q[2 * jj] * invV);
        float v1 = fmaf(-m1, m1, q[2 * jj + 1] * invV);
        pk[jj] = bf_rne(v0) | (bf_rne(v1) << 16);
    }

    // permute to B-fragment layout: target lane L gets (voxel L&15, quarter L>>4)
    // which lives in source lane (L&15)*4 + (L>>4)
    uint4 bu;
    {
        int srcl = ((lane & 15) << 2) + (lane >> 4);
        bu.x = (unsigned)__shfl((int)pk[0], srcl);
        bu.y = (unsigned)__shfl((int)pk[1], srcl);
        bu.z = (unsigned)__shfl((int)pk[2], srcl);
        bu.w = (unsigned)__shfl((int)pk[3], srcl);
    }
    short8 bfrag = __builtin_bit_cast(short8, bu);
    short8 afrag0 = __builtin_bit_cast(short8, a0u);
    short8 afrag1 = __builtin_bit_cast(short8, a1u);

    floatx4 z = {0.f, 0.f, 0.f, 0.f};
    // D[m=tap][n=voxel-in-wave]; lane L: col=L&15, rows=(L>>4)*4+r
    floatx4 t0 = __builtin_amdgcn_mfma_f32_16x16x32_bf16(afrag0, bfrag, z, 0, 0, 0);
    floatx4 t1 = __builtin_amdgcn_mfma_f32_16x16x32_bf16(afrag1, bfrag, z, 0, 0, 0);

    // store taps straight to the 27 T planes (wave covers pixels pixb+wv*16..+15)
    const unsigned gidx = (unsigned)(b * PLANE + d * HW_ + pixb + ((tid >> 6) << 4) + (lane & 15));
    const int tq = (lane >> 4) << 2;
#pragma unroll
    for (int r = 0; r < 4; ++r) {
        T[(unsigned)((tq + r) * NVOX) + gidx] = t0[r];
        int tap2 = 16 + tq + r;
        if (tap2 < 27) T[(unsigned)(tap2 * NVOX) + gidx] = t1[r];
    }
}

// cost[p] = sum_j T_j[p + off_j], SAME zero padding (per-batch d,h,w bounds)
__global__ __launch_bounds__(256) void cost_kernel(const float* __restrict__ T,
                                                   float* __restrict__ cost) {
    int vox = blockIdx.x * 256 + threadIdx.x;
    if (vox >= NVOX) return;
    int w = vox % W_;
    int h = (vox / W_) % H_;
    int d = (vox / HW_) % D_;
    float acc = 0.f;
#pragma unroll
    for (int kd = 0; kd < 3; ++kd) {
        int dd = d + kd - 1;
        if (dd < 0 || dd >= D_) continue;
#pragma unroll
        for (int kh = 0; kh < 3; ++kh) {
            int hh = h + kh - 1;
            if (hh < 0 || hh >= H_) continue;
#pragma unroll
            for (int kw = 0; kw < 3; ++kw) {
                int ww = w + kw - 1;
                if (ww < 0 || ww >= W_) continue;
                int j = kd * 9 + kh * 3 + kw;
                acc += T[(unsigned)(j * NVOX) + (unsigned)(vox + (kd - 1) * HW_ + (kh - 1) * W_ + (kw - 1))];
            }
        }
    }
    cost[vox] = acc;
}

// softmax over D + depth + conf + itg
__global__ __launch_bounds__(256) void out_kernel(const float* __restrict__ cost,
                                                  const float* __restrict__ dv,
                                                  float* __restrict__ out) {
    int tid = blockIdx.x * 256 + threadIdx.x;  // over B*HW
    if (tid >= B_ * HW_) return;
    int pix = tid % HW_;
    int b = tid / HW_;
    const float* cb = cost + (size_t)b * PLANE + pix;
    float p[D_];
    float mx = -1e30f;
#pragma unroll
    for (int d = 0; d < D_; ++d) {
        p[d] = cb[(size_t)d * HW_];
        mx = fmaxf(mx, p[d]);
    }
    float S = 0.f;
#pragma unroll
    for (int d = 0; d < D_; ++d) {
        p[d] = expf(p[d] - mx);
        S += p[d];
    }
    float invS = 1.f / S;
    float S2 = 0.f;
#pragma unroll
    for (int d = 0; d < D_; ++d) {
        p[d] *= invS;            // prob
        S2 += p[d];
    }
    float invS2 = 1.f / fmaxf(S2, 1e-12f);
    float depth = 0.f, dif = 0.f;
#pragma unroll
    for (int d = 0; d < D_; ++d) {
        depth = fmaf(p[d] * invS2, dv[b * D_ + d], depth);
        dif = fmaf(p[d], (float)d, dif);
    }
    int di = (int)dif;
    di = min(max(di, 0), D_ - 1);
    float conf = 0.f;
#pragma unroll
    for (int k = -1; k <= 2; ++k) {
        int idx = di + k;
        if (idx >= 0 && idx < D_) conf += p[idx];
    }
    out[tid] = depth;
    out[B_ * HW_ + tid] = conf;
    float* itg = out + 2 * B_ * HW_ + (size_t)b * PLANE + pix;
#pragma unroll
    for (int d = 0; d < D_; ++d) itg[(size_t)d * HW_] = p[d] * invS2;
}

extern "C" void kernel_launch(void* const* d_in, const int* in_sizes, int n_in,
                              void* d_out, int out_size, void* d_ws, size_t ws_size,
                              hipStream_t stream) {
    const float* feat = (const float*)d_in[0];   // (B,V,C,H,W)
    const float* proj = (const float*)d_in[1];   // (B,V,2,4,4)
    const float* dv   = (const float*)d_in[2];   // (B,D)
    const float* wreg = (const float*)d_in[3];   // (1,C,3,3,3)
    float* out = (float*)d_out;
    float* ws = (float*)d_ws;

    // workspace layout (floats)
    const size_t rt_off = 0;
    const size_t rt_sz = 128;
    const size_t wtb_off = rt_off + rt_sz;
    const size_t wtb_sz = 512;                            // 2*64*4 uints
    const size_t fcl_off = wtb_off + wtb_sz;
    const size_t fcl_sz = (size_t)B_ * V_ * HW_ * 16;     // bf16 pixels: 16 uints each
    const size_t T_off = fcl_off + fcl_sz;
    const size_t T_sz = (size_t)27 * NVOX;                // 53,084,160
    const size_t cost_off = T_off + T_sz;
    const size_t cost_sz = (size_t)NVOX;                  // 1,966,080
    const size_t need = (cost_off + cost_sz) * sizeof(float);
    if (ws_size < need) return;  // workspace too small — fail loudly

    float* rt = ws + rt_off;
    unsigned* wtb = (unsigned*)(ws + wtb_off);
    unsigned* feat_cl = (unsigned*)(ws + fcl_off);
    float* T = ws + T_off;
    float* cost = ws + cost_off;

    setup_kernel<<<1, 128, 0, stream>>>(proj, wreg, rt, wtb);
    transpose_kernel<<<(B_ * V_ * HW_) / 256, 256, 0, stream>>>(feat, feat_cl);
    dim3 wgrid(HW_ / 64, D_, B_);
    warp_kernel<<<wgrid, 256, 0, stream>>>((const unsigned char*)feat_cl, rt, dv, wtb, T);
    cost_kernel<<<NVOX / 256, 256, 0, stream>>>(T, cost);
    out_kernel<<<(B_ * HW_ + 255) / 256, 256, 0, stream>>>(cost, dv, out);
}

// Round 9
// 242.624 us; speedup vs baseline: 2.5063x; 1.0255x over previous
//
#include <hip/hip_runtime.h>
#include <math.h>

// Problem constants (from setup_inputs): B,V,C,D,H,W = 2,5,32,48,128,160
constexpr int B_ = 2;
constexpr int V_ = 5;
constexpr int C_ = 32;
constexpr int D_ = 48;
constexpr int H_ = 128;
constexpr int W_ = 160;
constexpr int HW_ = H_ * W_;               // 20480
constexpr int NVOX = B_ * D_ * HW_;        // 1,966,080
constexpr int PLANE = D_ * HW_;            // 983,040 (per-batch voxels)

typedef short short8 __attribute__((ext_vector_type(8)));
typedef float floatx4 __attribute__((ext_vector_type(4)));

// ---------------- small matrix helpers (device) ----------------

__device__ inline void combine4(const float* pm, float out[4][4]) {
    const float* E = pm;
    const float* K = pm + 16;
    for (int i = 0; i < 3; ++i)
        for (int j = 0; j < 4; ++j) {
            float a = 0.f;
            for (int k = 0; k < 3; ++k) a += K[i * 4 + k] * E[k * 4 + j];
            out[i][j] = a;
        }
    for (int j = 0; j < 4; ++j) out[3][j] = E[12 + j];
}

__device__ inline void invert4(const float A[4][4], float inv[4][4]) {
    float M[4][8];
    for (int i = 0; i < 4; ++i)
        for (int j = 0; j < 4; ++j) {
            M[i][j] = A[i][j];
            M[i][4 + j] = (i == j) ? 1.f : 0.f;
        }
    for (int col = 0; col < 4; ++col) {
        int piv = col;
        float best = fabsf(M[col][col]);
        for (int r = col + 1; r < 4; ++r) {
            float v = fabsf(M[r][col]);
            if (v > best) { best = v; piv = r; }
        }
        if (piv != col)
            for (int j = 0; j < 8; ++j) { float t = M[col][j]; M[col][j] = M[piv][j]; M[piv][j] = t; }
        float ip = 1.f / M[col][col];
        for (int j = 0; j < 8; ++j) M[col][j] *= ip;
        for (int r = 0; r < 4; ++r) {
            if (r == col) continue;
            float f = M[r][col];
            for (int j = 0; j < 8; ++j) M[r][j] -= f * M[col][j];
        }
    }
    for (int i = 0; i < 4; ++i)
        for (int j = 0; j < 4; ++j) inv[i][j] = M[i][4 + j];
}

__device__ inline unsigned bf_rne(float f) {
    unsigned u = __float_as_uint(f);
    return (u + 0x7FFFu + ((u >> 16) & 1u)) >> 16;   // RNE (values are finite)
}

// setup: (a) per b,v: P = src_proj @ inv(ref_proj) -> rt[12 floats]
//        (b) prepack conv weights as bf16 MFMA A-fragments:
//            A[m=tap=lane&15 (+16i)][k=ch=(lane>>4)*8+j], taps>=27 zero-padded
__global__ void setup_kernel(const float* __restrict__ proj, const float* __restrict__ wreg,
                             float* __restrict__ rt, unsigned* __restrict__ wtb) {
    int t = threadIdx.x;
    if (t < B_) {
        int b = t;
        float ref[4][4], inv[4][4];
        combine4(proj + (size_t)((b * V_ + 0) * 2) * 16, ref);
        invert4(ref, inv);
        for (int v = 1; v < V_; ++v) {
            float src[4][4];
            combine4(proj + (size_t)((b * V_ + v) * 2) * 16, src);
            float P[3][4];
            for (int i = 0; i < 3; ++i)
                for (int j = 0; j < 4; ++j) {
                    float a = 0.f;
                    for (int k = 0; k < 4; ++k) a += src[i][k] * inv[k][j];
                    P[i][j] = a;
                }
            float* o = rt + (size_t)(b * (V_ - 1) + (v - 1)) * 12;
            o[0] = P[0][0]; o[1] = P[0][1]; o[2] = P[0][2];
            o[3] = P[1][0]; o[4] = P[1][1]; o[5] = P[1][2];
            o[6] = P[2][0]; o[7] = P[2][1]; o[8] = P[2][2];
            o[9] = P[0][3]; o[10] = P[1][3]; o[11] = P[2][3];
        }
    }
    if (t < 128) {
        int i = t >> 6;          // which mfma (taps 0-15 / 16-31)
        int lane = t & 63;
        int q = lane >> 4;
        int l = lane & 15;
        int tap = i * 16 + l;
        unsigned u[4];
#pragma unroll
        for (int jj = 0; jj < 4; ++jj) {
            int ch0 = q * 8 + 2 * jj;
            float v0 = (tap < 27) ? wreg[ch0 * 27 + tap] : 0.f;
            float v1 = (tap < 27) ? wreg[(ch0 + 1) * 27 + tap] : 0.f;
            u[jj] = bf_rne(v0) | (bf_rne(v1) << 16);
        }
        uint4* o = (uint4*)wtb;
        o[i * 64 + lane] = make_uint4(u[0], u[1], u[2], u[3]);
    }
}

// transpose features (B,V,C,H,W) f32 -> channel-last bf16 (B,V,H,W,C): 64 B/pixel
__global__ __launch_bounds__(256) void transpose_kernel(const float* __restrict__ feat,
                                                        unsigned* __restrict__ feat_cl) {
    int idx = blockIdx.x * 256 + threadIdx.x;  // over B*V*HW
    if (idx >= B_ * V_ * HW_) return;
    int pix = idx % HW_;
    int bv = idx / HW_;
    const float* src = feat + (size_t)bv * C_ * HW_ + pix;
    unsigned u[16];
#pragma unroll
    for (int j = 0; j < 16; ++j) {
        float a = src[(size_t)(2 * j) * HW_];
        float b = src[(size_t)(2 * j + 1) * HW_];
        u[j] = bf_rne(a) | (bf_rne(b) << 16);
    }
    uint4* dst = (uint4*)(feat_cl + (size_t)idx * 16);
    dst[0] = make_uint4(u[0], u[1], u[2], u[3]);
    dst[1] = make_uint4(u[4], u[5], u[6], u[7]);
    dst[2] = make_uint4(u[8], u[9], u[10], u[11]);
    dst[3] = make_uint4(u[12], u[13], u[14], u[15]);
}

// Fused homography warp + bilinear + variance + conv channel-reduction.
// Block = 256 threads = 64 pixels x 4 channel-quarter lanes; grid (320, D, B)
// so b/d/depth are wave-uniform (SGPR). bf16 channel-last features: one 16B
// load covers a corner's 8 channels. Lane cq of each quad computes view cq's
// projection; weights+offsets broadcast per view via quad shfl (small live
// set — R6's up-front hoist spilled). T-dot on MFMA; 27 tap planes stored
// straight from MFMA regs as bf16 (halves the T round-trip: pre-softmax
// intermediate, rounding same order as existing bf16-variance error).
// T layout: [j=0..26][b][d][h][w], ushort.
__global__ __launch_bounds__(256) void warp_kernel(const unsigned char* __restrict__ fb,
                                                   const float* __restrict__ rt,
                                                   const float* __restrict__ dv,
                                                   const unsigned* __restrict__ wtb,
                                                   unsigned short* __restrict__ T) {
    const int tid = threadIdx.x;
    const int lane = tid & 63;
    const int cq = tid & 3;                   // channel quarter
    const int b = blockIdx.z;
    const int d = blockIdx.y;
    const int pixb = blockIdx.x * 64;         // block's first pixel
    const int pix = pixb + (tid >> 2);
    const int w = pix % W_;
    const int h = pix / W_;
    const float wf = (float)w, hf = (float)h;
    const float dep = dv[b * D_ + d];         // uniform -> s_load

    // A-fragments (bf16 conv weights), constant per lane
    const uint4* wp = (const uint4*)wtb;
    uint4 a0u = wp[lane];
    uint4 a1u = wp[64 + lane];

    // own view (cq): projection + bilinear weights + corner pixel indices
    float w00, w01, w10, w11;
    int pix00, pix01, pix10, pix11;
    {
        const float* m = rt + (b * (V_ - 1) + cq) * 12;
        float xp = fmaf(fmaf(m[0], wf, fmaf(m[1], hf, m[2])), dep, m[9]);
        float yp = fmaf(fmaf(m[3], wf, fmaf(m[4], hf, m[5])), dep, m[10]);
        float zp = fmaf(fmaf(m[6], wf, fmaf(m[7], hf, m[8])), dep, m[11]);
        float iz = __builtin_amdgcn_rcpf(zp);
        float ix = xp * iz, iy = yp * iz;
        float x0f = floorf(ix), y0f = floorf(iy);
        float wx1 = ix - x0f, wx0 = 1.f - wx1;
        float wy1 = iy - y0f, wy0 = 1.f - wy1;
        float x1f = x0f + 1.f, y1f = y0f + 1.f;
        bool vx0 = (x0f >= 0.f) && (x0f <= (float)(W_ - 1));
        bool vx1 = (x1f >= 0.f) && (x1f <= (float)(W_ - 1));
        bool vy0 = (y0f >= 0.f) && (y0f <= (float)(H_ - 1));
        bool vy1 = (y1f >= 0.f) && (y1f <= (float)(H_ - 1));
        int x0i = (int)fminf(fmaxf(x0f, 0.f), (float)(W_ - 1));
        int x1i = (int)fminf(fmaxf(x1f, 0.f), (float)(W_ - 1));
        int y0i = (int)fminf(fmaxf(y0f, 0.f), (float)(H_ - 1));
        int y1i = (int)fminf(fmaxf(y1f, 0.f), (float)(H_ - 1));
        w00 = wx0 * wy0 * ((vx0 && vy0) ? 1.f : 0.f);
        w01 = wx1 * wy0 * ((vx1 && vy0) ? 1.f : 0.f);
        w10 = wx0 * wy1 * ((vx0 && vy1) ? 1.f : 0.f);
        w11 = wx1 * wy1 * ((vx1 && vy1) ? 1.f : 0.f);
        pix00 = y0i * W_ + x0i;
        pix01 = y0i * W_ + x1i;
        pix10 = y1i * W_ + x0i;
        pix11 = y1i * W_ + x1i;
    }

    // ref view: own pixel, own 8 channels (bf16x8 = one 16B load)
    float s[8], q[8];
    {
        const unsigned char* rb = fb + (size_t)(b * V_) * HW_ * 64;
        uint4 r = *(const uint4*)(rb + (((unsigned)pix) << 6) + (cq << 4));
        float f0 = __uint_as_float(r.x << 16);
        float f1 = __uint_as_float(r.x & 0xffff0000u);
        float f2 = __uint_as_float(r.y << 16);
        float f3 = __uint_as_float(r.y & 0xffff0000u);
        float f4 = __uint_as_float(r.z << 16);
        float f5 = __uint_as_float(r.z & 0xffff0000u);
        float f6 = __uint_as_float(r.w << 16);
        float f7 = __uint_as_float(r.w & 0xffff0000u);
        s[0] = f0; s[1] = f1; s[2] = f2; s[3] = f3;
        s[4] = f4; s[5] = f5; s[6] = f6; s[7] = f7;
        q[0] = f0 * f0; q[1] = f1 * f1; q[2] = f2 * f2; q[3] = f3 * f3;
        q[4] = f4 * f4; q[5] = f5 * f5; q[6] = f6 * f6; q[7] = f7 * f7;
    }

#pragma unroll
    for (int v = 0; v < V_ - 1; ++v) {
        int sl = (lane & ~3) | v;             // quad-local broadcast source
        float W00 = __shfl(w00, sl), W01 = __shfl(w01, sl);
        float W10 = __shfl(w10, sl), W11 = __shfl(w11, sl);
        unsigned O00 = ((unsigned)__shfl(pix00, sl) << 6) + (cq << 4);
        unsigned O01 = ((unsigned)__shfl(pix01, sl) << 6) + (cq << 4);
        unsigned O10 = ((unsigned)__shfl(pix10, sl) << 6) + (cq << 4);
        unsigned O11 = ((unsigned)__shfl(pix11, sl) << 6) + (cq << 4);
        const unsigned char* base = fb + (size_t)(b * V_ + v + 1) * HW_ * 64;
        uint4 c0 = *(const uint4*)(base + O00);
        uint4 c1 = *(const uint4*)(base + O01);
        uint4 c2 = *(const uint4*)(base + O10);
        uint4 c3 = *(const uint4*)(base + O11);
        unsigned u0[4] = {c0.x, c0.y, c0.z, c0.w};
        unsigned u1[4] = {c1.x, c1.y, c1.z, c1.w};
        unsigned u2[4] = {c2.x, c2.y, c2.z, c2.w};
        unsigned u3[4] = {c3.x, c3.y, c3.z, c3.w};
#pragma unroll
        for (int jj = 0; jj < 4; ++jj) {
            float a0 = __uint_as_float(u0[jj] << 16);
            float b0 = __uint_as_float(u1[jj] << 16);
            float g0 = __uint_as_float(u2[jj] << 16);
            float d0 = __uint_as_float(u3[jj] << 16);
            float acc = fmaf(a0, W00, fmaf(b0, W01, fmaf(g0, W10, d0 * W11)));
            s[2 * jj] += acc;
            q[2 * jj] = fmaf(acc, acc, q[2 * jj]);
            float a1 = __uint_as_float(u0[jj] & 0xffff0000u);
            float b1 = __uint_as_float(u1[jj] & 0xffff0000u);
            float g1 = __uint_as_float(u2[jj] & 0xffff0000u);
            float d1 = __uint_as_float(u3[jj] & 0xffff0000u);
            float acc1 = fmaf(a1, W00, fmaf(b1, W01, fmaf(g1, W10, d1 * W11)));
            s[2 * jj + 1] += acc1;
            q[2 * jj + 1] = fmaf(acc1, acc1, q[2 * jj + 1]);
        }
    }

    // variance for this thread's 8 channels, packed to bf16
    const float invV = 1.0f / (float)V_;
    unsigned pk[4];
#pragma unroll
    for (int jj = 0; jj < 4; ++jj) {
        float m0 = s[2 * jj] * invV, m1 = s[2 * jj + 1] * invV;
        float v0 = fmaf(-m0, m0, q[2 * jj] * invV);
        float v1 = fmaf(-m1, m1, q[2 * jj + 1] * invV);
        pk[jj] = bf_rne(v0) | (bf_rne(v1) << 16);
    }

    // permute to B-fragment layout: target lane L gets (voxel L&15, quarter L>>4)
    // which lives in source lane (L&15)*4 + (L>>4)
    uint4 bu;
    {
        int srcl = ((lane & 15) << 2) + (lane >> 4);
        bu.x = (unsigned)__shfl((int)pk[0], srcl);
        bu.y = (unsigned)__shfl((int)pk[1], srcl);
        bu.z = (unsigned)__shfl((int)pk[2], srcl);
        bu.w = (unsigned)__shfl((int)pk[3], srcl);
    }
    short8 bfrag = __builtin_bit_cast(short8, bu);
    short8 afrag0 = __builtin_bit_cast(short8, a0u);
    short8 afrag1 = __builtin_bit_cast(short8, a1u);

    floatx4 z = {0.f, 0.f, 0.f, 0.f};
    // D[m=tap][n=voxel-in-wave]; lane L: col=L&15, rows=(L>>4)*4+r
    floatx4 t0 = __builtin_amdgcn_mfma_f32_16x16x32_bf16(afrag0, bfrag, z, 0, 0, 0);
    floatx4 t1 = __builtin_amdgcn_mfma_f32_16x16x32_bf16(afrag1, bfrag, z, 0, 0, 0);

    // store taps as bf16 straight to the 27 T planes
    const unsigned gidx = (unsigned)(b * PLANE + d * HW_ + pixb + ((tid >> 6) << 4) + (lane & 15));
    const int tq = (lane >> 4) << 2;
#pragma unroll
    for (int r = 0; r < 4; ++r) {
        T[(unsigned)((tq + r) * NVOX) + gidx] = (unsigned short)bf_rne(t0[r]);
        int tap2 = 16 + tq + r;
        if (tap2 < 27) T[(unsigned)(tap2 * NVOX) + gidx] = (unsigned short)bf_rne(t1[r]);
    }
}

// cost[p] = sum_j T_j[p + off_j], SAME zero padding (per-batch d,h,w bounds)
__global__ __launch_bounds__(256) void cost_kernel(const unsigned short* __restrict__ T,
                                                   float* __restrict__ cost) {
    int vox = blockIdx.x * 256 + threadIdx.x;
    if (vox >= NVOX) return;
    int w = vox % W_;
    int h = (vox / W_) % H_;
    int d = (vox / HW_) % D_;
    float acc = 0.f;
#pragma unroll
    for (int kd = 0; kd < 3; ++kd) {
        int dd = d + kd - 1;
        if (dd < 0 || dd >= D_) continue;
#pragma unroll
        for (int kh = 0; kh < 3; ++kh) {
            int hh = h + kh - 1;
            if (hh < 0 || hh >= H_) continue;
#pragma unroll
            for (int kw = 0; kw < 3; ++kw) {
                int ww = w + kw - 1;
                if (ww < 0 || ww >= W_) continue;
                int j = kd * 9 + kh * 3 + kw;
                unsigned idx = (unsigned)(j * NVOX) + (unsigned)(vox + (kd - 1) * HW_ + (kh - 1) * W_ + (kw - 1));
                acc += __uint_as_float(((unsigned)T[idx]) << 16);
            }
        }
    }
    cost[vox] = acc;
}

// softmax over D + depth + conf + itg
__global__ __launch_bounds__(256) void out_kernel(const float* __restrict__ cost,
                                                  const float* __restrict__ dv,
                                                  float* __restrict__ out) {
    int tid = blockIdx.x * 256 + threadIdx.x;  // over B*HW
    if (tid >= B_ * HW_) return;
    int pix = tid % HW_;
    int b = tid / HW_;
    const float* cb = cost + (size_t)b * PLANE + pix;
    float p[D_];
    float mx = -1e30f;
#pragma unroll
    for (int d = 0; d < D_; ++d) {
        p[d] = cb[(size_t)d * HW_];
        mx = fmaxf(mx, p[d]);
    }
    float S = 0.f;
#pragma unroll
    for (int d = 0; d < D_; ++d) {
        p[d] = expf(p[d] - mx);
        S += p[d];
    }
    float invS = 1.f / S;
    float S2 = 0.f;
#pragma unroll
    for (int d = 0; d < D_; ++d) {
        p[d] *= invS;            // prob
        S2 += p[d];
    }
    float invS2 = 1.f / fmaxf(S2, 1e-12f);
    float depth = 0.f, dif = 0.f;
#pragma unroll
    for (int d = 0; d < D_; ++d) {
        depth = fmaf(p[d] * invS2, dv[b * D_ + d], depth);
        dif = fmaf(p[d], (float)d, dif);
    }
    int di = (int)dif;
    di = min(max(di, 0), D_ - 1);
    float conf = 0.f;
#pragma unroll
    for (int k = -1; k <= 2; ++k) {
        int idx = di + k;
        if (idx >= 0 && idx < D_) conf += p[idx];
    }
    out[tid] = depth;
    out[B_ * HW_ + tid] = conf;
    float* itg = out + 2 * B_ * HW_ + (size_t)b * PLANE + pix;
#pragma unroll
    for (int d = 0; d < D_; ++d) itg[(size_t)d * HW_] = p[d] * invS2;
}

extern "C" void kernel_launch(void* const* d_in, const int* in_sizes, int n_in,
                              void* d_out, int out_size, void* d_ws, size_t ws_size,
                              hipStream_t stream) {
    const float* feat = (const float*)d_in[0];   // (B,V,C,H,W)
    const float* proj = (const float*)d_in[1];   // (B,V,2,4,4)
    const float* dv   = (const float*)d_in[2];   // (B,D)
    const float* wreg = (const float*)d_in[3];   // (1,C,3,3,3)
    float* out = (float*)d_out;
    float* ws = (float*)d_ws;

    // workspace layout (floats)
    const size_t rt_off = 0;
    const size_t rt_sz = 128;
    const size_t wtb_off = rt_off + rt_sz;
    const size_t wtb_sz = 512;                            // 2*64*4 uints
    const size_t fcl_off = wtb_off + wtb_sz;
    const size_t fcl_sz = (size_t)B_ * V_ * HW_ * 16;     // bf16 pixels: 16 uints each
    const size_t T_off = fcl_off + fcl_sz;
    const size_t T_sz = (size_t)27 * NVOX / 2;            // bf16: 26,542,080 float-slots
    const size_t cost_off = T_off + T_sz;
    const size_t cost_sz = (size_t)NVOX;                  // 1,966,080
    const size_t need = (cost_off + cost_sz) * sizeof(float);
    if (ws_size < need) return;  // workspace too small — fail loudly

    float* rt = ws + rt_off;
    unsigned* wtb = (unsigned*)(ws + wtb_off);
    unsigned* feat_cl = (unsigned*)(ws + fcl_off);
    unsigned short* T = (unsigned short*)(ws + T_off);
    float* cost = ws + cost_off;

    setup_kernel<<<1, 128, 0, stream>>>(proj, wreg, rt, wtb);
    transpose_kernel<<<(B_ * V_ * HW_) / 256, 256, 0, stream>>>(feat, feat_cl);
    dim3 wgrid(HW_ / 64, D_, B_);
    warp_kernel<<<wgrid, 256, 0, stream>>>((const unsigned char*)feat_cl, rt, dv, wtb, T);
    cost_kernel<<<NVOX / 256, 256, 0, stream>>>(T, cost);
    out_kernel<<<(B_ * HW_ + 255) / 256, 256, 0, stream>>>(cost, dv, out);
}